// Round 6
// baseline (170.260 us; speedup 1.0000x reference)
//
#include <hip/hip_runtime.h>

// DNAS_DeformAxialDW: out = x + axial-deform-DW-conv_H(x) + axial-deform-DW-conv_W(x)
// Scalar fractional dilation r => each 7-tap conv folds into 13 integer taps with
// per-channel effective weights (precomputed into d_ws by taps_kernel).
//
// R1: register row-window -> L2-latency bound (214 us). R2/R3: global streaming ->
//     hoisting + spills (2GB/968MB scratch). R4: LDS tile, 18 reads/quad ->
//     LDS-pipe bound (213 us). R5: stream-from-LDS, 8 reads/quad -> 145 us, but
//     block lifecycle stage->drain->compute->exit leaves CU idle (VALUBusy 25%).
// R6: persistent block per plane + T14 async-stage: issue next tile's global
//     loads into registers BEFORE computing current tile from LDS; after compute,
//     barrier + ds_write regs + barrier. HBM latency hides under compute.

namespace {
constexpr int B = 8, C = 128, H = 224, W = 224;
constexpr int KT = 7;              // original taps
constexpr int M  = 6;              // max |integer offset| (r in [1,2])
constexpr int NT = 2 * M + 1;      // 13 effective integer taps
constexpr int TH = 32;             // output rows per tile
constexpr int NTILES = H / TH;     // 7
constexpr int SROWS = TH + 2 * M;  // 44 staged rows
constexpr int WQ = W / 4;          // 56 quads per row
constexpr int BLOCK = 448;         // 7 waves; 56 cols x 8 row-groups
constexpr int RPT = 4;             // output rows per thread
constexpr int WROWS = RPT + 2 * M; // 16 window rows per thread
constexpr int NSTAGE = SROWS * WQ; // 2464 staging quads
constexpr int PFK = (NSTAGE + BLOCK - 1) / BLOCK;  // 6 staging quads per thread
}

// Fold bilinear fractional taps into integer-offset effective weights.
// taps[c*NT + j]        = eh[c][offset j-M]   (H-axis)
// taps[C*NT + c*NT + j] = ew[c][offset j-M]   (W-axis)
__global__ void taps_kernel(const float* __restrict__ wh, const float* __restrict__ ww,
                            const float* __restrict__ r, float* __restrict__ taps) {
    int c = threadIdx.x;
    if (c >= C) return;
    float rv = fmaxf(r[0], 1.0f);  // jnp.clip(r, 1.0)
    float eh[NT], ew[NT];
    for (int j = 0; j < NT; ++j) { eh[j] = 0.f; ew[j] = 0.f; }
    for (int i = 0; i < KT; ++i) {
        float kpos  = (float)(i - KT / 2);
        float delta = kpos * rv;
        float d0f   = floorf(delta);
        float fr    = delta - d0f;
        int   j0    = (int)d0f + M;
        float whv = wh[c * KT + i];
        float wwv = ww[c * KT + i];
        if (j0 >= 0 && j0 < NT)         { eh[j0]   += (1.f - fr) * whv; ew[j0]   += (1.f - fr) * wwv; }
        if (j0 + 1 >= 0 && j0 + 1 < NT) { eh[j0+1] += fr * whv;         ew[j0+1] += fr * wwv; }
    }
    for (int j = 0; j < NT; ++j) {
        taps[c * NT + j]          = eh[j];
        taps[C * NT + c * NT + j] = ew[j];
    }
}

__global__ __launch_bounds__(BLOCK) void deform_axial_kernel(
    const float* __restrict__ x, const float* __restrict__ taps,
    float* __restrict__ out) {
    __shared__ float lds[SROWS][W];   // 44 x 224 x 4B = 39,424 B

    const int p   = blockIdx.x;       // plane (b*C + c) -- block-uniform
    const int c   = p & (C - 1);      // uniform -> taps via scalar loads
    const int tid = threadIdx.x;

    // per-channel effective taps: block-uniform address -> SGPRs
    float eh[NT], ew[NT];
    const float* __restrict__ ehp = taps + c * NT;
    const float* __restrict__ ewp = taps + C * NT + c * NT;
#pragma unroll
    for (int j = 0; j < NT; ++j) { eh[j] = ehp[j]; ew[j] = ewp[j]; }

    const long base = (long)p * (H * W);
    const float* __restrict__ xp = x + base;
    float* __restrict__ outp_base = out + base;
    const float4 zero4 = make_float4(0.f, 0.f, 0.f, 0.f);

    // staging coordinates (fixed per thread): quad q = tid + k*BLOCK
    int srow[PFK], scol[PFK];
    bool sact[PFK];
#pragma unroll
    for (int k = 0; k < PFK; ++k) {
        const int q = tid + k * BLOCK;
        sact[k] = (q < NSTAGE);
        srow[k] = q / WQ;
        scol[k] = q % WQ;
    }

    // ---- initial stage: tile 0 window = global rows -6..37 ----
#pragma unroll
    for (int k = 0; k < PFK; ++k) {
        if (sact[k]) {
            const int gr = srow[k] - M;
            float4 v = zero4;
            if (gr >= 0)  // gr <= 37 < H always
                v = *reinterpret_cast<const float4*>(xp + gr * W + scol[k] * 4);
            *reinterpret_cast<float4*>(&lds[srow[k]][scol[k] * 4]) = v;
        }
    }
    __syncthreads();

    const int cq = tid % WQ;        // column quad 0..55
    const int rg = tid / WQ;        // row group 0..7
    const int r0 = rg * RPT;        // first output row within tile

    for (int t = 0; t < NTILES; ++t) {
        const int h0 = t * TH;
        const bool do_pf = (t + 1 < NTILES);

        // ---- issue next tile's loads into registers (async-stage split) ----
        // tile t+1 window = global rows h0+26 .. h0+69
        float4 pf[PFK];
#pragma unroll
        for (int k = 0; k < PFK; ++k) {
            pf[k] = zero4;
            if (do_pf && sact[k]) {
                const int gr = h0 + TH - M + srow[k];
                if (gr < H)   // gr >= 26 always
                    pf[k] = *reinterpret_cast<const float4*>(xp + gr * W + scol[k] * 4);
            }
        }

        // ---- compute tile t from LDS (stream 16 window rows, 4 accumulators) ----
        float4 acc[RPT];
#pragma unroll
        for (int k = 0; k < RPT; ++k) acc[k] = zero4;

#pragma unroll
        for (int s = 0; s < WROWS; ++s) {
            const float4 q = *reinterpret_cast<const float4*>(&lds[r0 + s][cq * 4]);

            // H-axis: streamed row s is tap j = s-k for output row k
#pragma unroll
            for (int k = 0; k < RPT; ++k) {
                const int j = s - k;
                if (j >= 0 && j < NT) {
                    const float wgt = eh[j];
                    acc[k].x = fmaf(wgt, q.x, acc[k].x);
                    acc[k].y = fmaf(wgt, q.y, acc[k].y);
                    acc[k].z = fmaf(wgt, q.z, acc[k].z);
                    acc[k].w = fmaf(wgt, q.w, acc[k].w);
                }
            }

            // center row for output k = s - M: identity + W-conv
            if (s >= M && s < M + RPT) {
                const int k = s - M;
                const float* crow = &lds[r0 + s][0];
                float4 qm2 = (cq >= 2)      ? *reinterpret_cast<const float4*>(crow + (cq - 2) * 4) : zero4;
                float4 qm1 = (cq >= 1)      ? *reinterpret_cast<const float4*>(crow + (cq - 1) * 4) : zero4;
                float4 qp1 = (cq <= WQ - 2) ? *reinterpret_cast<const float4*>(crow + (cq + 1) * 4) : zero4;
                float4 qp2 = (cq <= WQ - 3) ? *reinterpret_cast<const float4*>(crow + (cq + 2) * 4) : zero4;

                float win[20];
                win[ 0] = qm2.x; win[ 1] = qm2.y; win[ 2] = qm2.z; win[ 3] = qm2.w;
                win[ 4] = qm1.x; win[ 5] = qm1.y; win[ 6] = qm1.z; win[ 7] = qm1.w;
                win[ 8] = q.x;   win[ 9] = q.y;   win[10] = q.z;   win[11] = q.w;
                win[12] = qp1.x; win[13] = qp1.y; win[14] = qp1.z; win[15] = qp1.w;
                win[16] = qp2.x; win[17] = qp2.y; win[18] = qp2.z; win[19] = qp2.w;

                // identity
                acc[k].x += q.x; acc[k].y += q.y; acc[k].z += q.z; acc[k].w += q.w;
                // element e at w = cq*4+e, tap j: win index = e + j + 2
#pragma unroll
                for (int j = 0; j < NT; ++j) {
                    const float wgt = ew[j];
                    acc[k].x = fmaf(wgt, win[2 + j], acc[k].x);
                    acc[k].y = fmaf(wgt, win[3 + j], acc[k].y);
                    acc[k].z = fmaf(wgt, win[4 + j], acc[k].z);
                    acc[k].w = fmaf(wgt, win[5 + j], acc[k].w);
                }
            }
        }

        // ---- store outputs (vmem stores, no LDS dependency) ----
        float* outp = outp_base + (long)(h0 + r0) * W + cq * 4;
#pragma unroll
        for (int k = 0; k < RPT; ++k) {
            *reinterpret_cast<float4*>(outp + k * W) = acc[k];
        }

        // ---- write prefetched tile into LDS for next iteration ----
        if (do_pf) {
            __syncthreads();   // everyone done reading current window
#pragma unroll
            for (int k = 0; k < PFK; ++k) {
                if (sact[k])
                    *reinterpret_cast<float4*>(&lds[srow[k]][scol[k] * 4]) = pf[k];
            }
            __syncthreads();   // new window visible
        }
    }
}

extern "C" void kernel_launch(void* const* d_in, const int* in_sizes, int n_in,
                              void* d_out, int out_size, void* d_ws, size_t ws_size,
                              hipStream_t stream) {
    const float* x  = (const float*)d_in[0];
    const float* wh = (const float*)d_in[1];
    const float* ww = (const float*)d_in[2];
    const float* r  = (const float*)d_in[3];
    float* out  = (float*)d_out;
    float* taps = (float*)d_ws;  // needs 2*C*NT*4 = 13,312 bytes

    hipLaunchKernelGGL(taps_kernel, dim3(1), dim3(C), 0, stream, wh, ww, r, taps);
    hipLaunchKernelGGL(deform_axial_kernel, dim3(B * C), dim3(BLOCK),
                       0, stream, x, taps, out);
}

// Round 7
// 124.226 us; speedup vs baseline: 1.3706x; 1.3706x over previous
//
#include <hip/hip_runtime.h>
#include <stdint.h>

// DNAS_DeformAxialDW: out = x + axial-deform-DW-conv_H(x) + axial-deform-DW-conv_W(x)
// Scalar fractional dilation r => each 7-tap conv folds into 13 integer taps with
// per-channel effective weights (precomputed into d_ws by taps_kernel).
//
// R1: register row-window -> latency bound (214 us). R2/R3: global streaming ->
//     hoisting + spills. R4: LDS tile, 18 reads/quad -> LDS-pipe bound (213 us).
// R5: stream-from-LDS, 8 reads/quad -> 145 us. Conflict counter identical to R4
//     (1.583e7) despite 2.25x fewer reads => conflicts come from staging
//     ds_write_b128, not reads.
// R6: persistent+reg-prefetch -> VGPR 128, occupancy halved, 170 us. REVERTED.
// R7: R5 structure, but stage via __builtin_amdgcn_global_load_lds (width=16):
//     no ds_write, no VGPR round-trip, no write-side conflicts. OOB halo rows
//     get zeros by redirecting the per-lane GLOBAL source to a zero region in
//     d_ws (LDS dest must stay linear, rule #21).

namespace {
constexpr int B = 8, C = 128, H = 224, W = 224;
constexpr int KT = 7;              // original taps
constexpr int M  = 6;              // max |integer offset| (r in [1,2])
constexpr int NT = 2 * M + 1;      // 13 effective integer taps
constexpr int TH = 32;             // output rows per tile
constexpr int HTILES = H / TH;     // 7
constexpr int SROWS = TH + 2 * M;  // 44 staged rows
constexpr int WQ = W / 4;          // 56 quads per row
constexpr int BLOCK = 448;         // 7 waves; 56 cols x 8 row-groups
constexpr int RPT = 4;             // output rows per thread
constexpr int WROWS = RPT + 2 * M; // 16 window rows per thread
constexpr int NSTAGE = SROWS * WQ; // 2464 staging quads
constexpr int QPW = 384;           // staging quads per wave (6 chunks x 64)
constexpr int ZOFF = 2 * C * NT;   // zeros region offset in d_ws (floats) = 3328
}

typedef __attribute__((address_space(3))) uint32_t lds_u32;
typedef __attribute__((address_space(1))) const uint32_t gbl_u32;

// Fold bilinear fractional taps into integer-offset effective weights; also
// zero-fill the 256-float OOB source region at taps+ZOFF.
// taps[c*NT + j]        = eh[c][offset j-M]   (H-axis)
// taps[C*NT + c*NT + j] = ew[c][offset j-M]   (W-axis)
__global__ void taps_kernel(const float* __restrict__ wh, const float* __restrict__ ww,
                            const float* __restrict__ r, float* __restrict__ taps) {
    int c = threadIdx.x;
    if (c >= C) return;
    taps[ZOFF + c]       = 0.f;   // zero region for OOB staging reads
    taps[ZOFF + C + c]   = 0.f;
    float rv = fmaxf(r[0], 1.0f);  // jnp.clip(r, 1.0)
    float eh[NT], ew[NT];
    for (int j = 0; j < NT; ++j) { eh[j] = 0.f; ew[j] = 0.f; }
    for (int i = 0; i < KT; ++i) {
        float kpos  = (float)(i - KT / 2);
        float delta = kpos * rv;
        float d0f   = floorf(delta);
        float fr    = delta - d0f;
        int   j0    = (int)d0f + M;
        float whv = wh[c * KT + i];
        float wwv = ww[c * KT + i];
        if (j0 >= 0 && j0 < NT)         { eh[j0]   += (1.f - fr) * whv; ew[j0]   += (1.f - fr) * wwv; }
        if (j0 + 1 >= 0 && j0 + 1 < NT) { eh[j0+1] += fr * whv;         ew[j0+1] += fr * wwv; }
    }
    for (int j = 0; j < NT; ++j) {
        taps[c * NT + j]          = eh[j];
        taps[C * NT + c * NT + j] = ew[j];
    }
}

__global__ __launch_bounds__(BLOCK) void deform_axial_kernel(
    const float* __restrict__ x, const float* __restrict__ taps,
    float* __restrict__ out) {
    __shared__ float lds0[SROWS * W];   // 44 x 224 x 4B = 39,424 B (linear!)

    const int p    = blockIdx.y;        // plane (b*C + c) -- block-uniform
    const int c    = p & (C - 1);       // uniform -> taps via scalar loads
    const int h0   = blockIdx.x * TH;   // tile's first output row
    const int tid  = threadIdx.x;
    const int wave = tid >> 6;
    const int lane = tid & 63;

    const long base = (long)p * (H * W);
    const float* __restrict__ xp = x + base;

    // ---- async stage: rows h0-6 .. h0+37 into LDS via global_load_lds ----
    // Global source is linear in quad index q (rows contiguous); LDS dest is
    // linear chunk base + lane*16 (HW). OOB rows read the zero region in d_ws.
    {
        const float* gwin  = xp + (h0 - M) * W;       // window start (may precede xp)
        const float* zbase = taps + ZOFF + lane * 4;  // per-lane slot in zero region
#pragma unroll
        for (int k = 0; k < 6; ++k) {
            const int q = wave * QPW + k * 64 + lane;
            if (q < NSTAGE) {
                const int  row   = q / WQ;                       // 0..43
                const bool valid = (unsigned)(h0 - M + row) < (unsigned)H;
                const float* src = valid ? (gwin + q * 4) : zbase;
                float* dst = lds0 + (q & ~63) * 4;               // wave-uniform chunk base
                __builtin_amdgcn_global_load_lds((gbl_u32*)src, (lds_u32*)dst, 16, 0, 0);
            }
        }
    }

    // per-channel effective taps: block-uniform address -> SGPRs (overlaps loads)
    float eh[NT], ew[NT];
    const float* __restrict__ ehp = taps + c * NT;
    const float* __restrict__ ewp = taps + C * NT + c * NT;
#pragma unroll
    for (int j = 0; j < NT; ++j) { eh[j] = ehp[j]; ew[j] = ewp[j]; }

    __syncthreads();

    // ---- compute: thread owns 4 consecutive output rows x 1 quad ----
    // Stream the 16 window rows once; each feeds <=4 accumulators (H-conv). When
    // the streamed row is a center row (s-6 in [0,RPT)), add identity + W-conv.
    const int cq = tid % WQ;        // column quad 0..55
    const int rg = tid / WQ;        // row group 0..7
    const int r0 = rg * RPT;        // first output row within tile
    const float4 zero4 = make_float4(0.f, 0.f, 0.f, 0.f);

    float4 acc[RPT];
#pragma unroll
    for (int k = 0; k < RPT; ++k) acc[k] = zero4;

#pragma unroll
    for (int s = 0; s < WROWS; ++s) {
        const float4 q = *reinterpret_cast<const float4*>(&lds0[(r0 + s) * W + cq * 4]);

        // H-axis: streamed row s is tap j = s-k for output row k
#pragma unroll
        for (int k = 0; k < RPT; ++k) {
            const int j = s - k;
            if (j >= 0 && j < NT) {
                const float wgt = eh[j];
                acc[k].x = fmaf(wgt, q.x, acc[k].x);
                acc[k].y = fmaf(wgt, q.y, acc[k].y);
                acc[k].z = fmaf(wgt, q.z, acc[k].z);
                acc[k].w = fmaf(wgt, q.w, acc[k].w);
            }
        }

        // center row for output k = s - M: identity + W-conv
        if (s >= M && s < M + RPT) {
            const int k = s - M;
            const float* crow = &lds0[(r0 + s) * W];
            float4 qm2 = (cq >= 2)      ? *reinterpret_cast<const float4*>(crow + (cq - 2) * 4) : zero4;
            float4 qm1 = (cq >= 1)      ? *reinterpret_cast<const float4*>(crow + (cq - 1) * 4) : zero4;
            float4 qp1 = (cq <= WQ - 2) ? *reinterpret_cast<const float4*>(crow + (cq + 1) * 4) : zero4;
            float4 qp2 = (cq <= WQ - 3) ? *reinterpret_cast<const float4*>(crow + (cq + 2) * 4) : zero4;

            float win[20];
            win[ 0] = qm2.x; win[ 1] = qm2.y; win[ 2] = qm2.z; win[ 3] = qm2.w;
            win[ 4] = qm1.x; win[ 5] = qm1.y; win[ 6] = qm1.z; win[ 7] = qm1.w;
            win[ 8] = q.x;   win[ 9] = q.y;   win[10] = q.z;   win[11] = q.w;
            win[12] = qp1.x; win[13] = qp1.y; win[14] = qp1.z; win[15] = qp1.w;
            win[16] = qp2.x; win[17] = qp2.y; win[18] = qp2.z; win[19] = qp2.w;

            // identity
            acc[k].x += q.x; acc[k].y += q.y; acc[k].z += q.z; acc[k].w += q.w;
            // element e at w = cq*4+e, tap j: win index = e + j + 2
#pragma unroll
            for (int j = 0; j < NT; ++j) {
                const float wgt = ew[j];
                acc[k].x = fmaf(wgt, win[2 + j], acc[k].x);
                acc[k].y = fmaf(wgt, win[3 + j], acc[k].y);
                acc[k].z = fmaf(wgt, win[4 + j], acc[k].z);
                acc[k].w = fmaf(wgt, win[5 + j], acc[k].w);
            }
        }
    }

    float* outp = out + base + (long)(h0 + r0) * W + cq * 4;
#pragma unroll
    for (int k = 0; k < RPT; ++k) {
        *reinterpret_cast<float4*>(outp + k * W) = acc[k];
    }
}

extern "C" void kernel_launch(void* const* d_in, const int* in_sizes, int n_in,
                              void* d_out, int out_size, void* d_ws, size_t ws_size,
                              hipStream_t stream) {
    const float* x  = (const float*)d_in[0];
    const float* wh = (const float*)d_in[1];
    const float* ww = (const float*)d_in[2];
    const float* r  = (const float*)d_in[3];
    float* out  = (float*)d_out;
    float* taps = (float*)d_ws;  // needs (2*C*NT + 256)*4 = 14,336 bytes

    hipLaunchKernelGGL(taps_kernel, dim3(1), dim3(C), 0, stream, wh, ww, r, taps);
    hipLaunchKernelGGL(deform_axial_kernel, dim3(HTILES, B * C), dim3(BLOCK),
                       0, stream, x, taps, out);
}

// Round 8
// 119.395 us; speedup vs baseline: 1.4260x; 1.0405x over previous
//
#include <hip/hip_runtime.h>
#include <stdint.h>

// DNAS_DeformAxialDW: out = x + axial-deform-DW-conv_H(x) + axial-deform-DW-conv_W(x)
// Scalar fractional dilation r => each 7-tap conv folds into 13 integer taps with
// per-channel effective weights (precomputed into d_ws by taps_kernel).
//
// R1: register window -> latency bound (214). R2/R3: unrolled global streaming ->
//     spills (919/429). R4: LDS tile, 18 reads/quad -> 213. R5: stream-from-LDS,
//     8 reads/quad -> 145. R6: reg-prefetch -> VGPR 128, occupancy halved, 170.
// R7: DMA staging (global_load_lds w=16) -> 124 us, traffic clean; but blocks
//     serialize stage-drain vs compute (VALUBusy 25%, occ 21%).
// R8: persistent per-plane block + double-buffered DMA pipeline with COUNTED
//     vmcnt (T3/T4-lite): stage tile t+1 into buf^1 while computing tile t from
//     buf; s_waitcnt vmcnt(10) (never 0) + raw s_barrier. Uniform 6 DMAs/wave
//     (dummy chunks -> scratch) keeps per-wave vmem counts exact.

namespace {
constexpr int B = 8, C = 128, H = 224, W = 224;
constexpr int KT = 7;              // original taps
constexpr int M  = 6;              // max |integer offset| (r in [1,2])
constexpr int NT = 2 * M + 1;      // 13 effective integer taps
constexpr int TH = 32;             // output rows per tile
constexpr int NTILES = H / TH;     // 7
constexpr int SROWS = TH + 2 * M;  // 44 staged rows
constexpr int WQ = W / 4;          // 56 quads per row
constexpr int BLOCK = 448;         // 7 waves; 56 cols x 8 row-groups
constexpr int RPT = 4;             // output rows per thread
constexpr int WROWS = RPT + 2 * M; // 16 window rows per thread
constexpr int NSTAGE = SROWS * WQ; // 2464 staging quads
constexpr int CHUNKS = 39;         // ceil(2464/64) real 1KB chunks
constexpr int BUF_FLOATS = 40 * 256;  // 39 real + 1 scratch chunk = 40,960 B
constexpr int ZOFF = 2 * C * NT;   // zero-region offset in d_ws (floats) = 3328
}

typedef __attribute__((address_space(3))) uint32_t lds_u32;
typedef __attribute__((address_space(1))) const uint32_t gbl_u32;

// Fold bilinear fractional taps into integer-offset effective weights; also
// zero-fill the 256-float OOB source region at taps+ZOFF.
__global__ void taps_kernel(const float* __restrict__ wh, const float* __restrict__ ww,
                            const float* __restrict__ r, float* __restrict__ taps) {
    int c = threadIdx.x;
    if (c >= C) return;
    taps[ZOFF + c]     = 0.f;   // zero region for OOB staging reads
    taps[ZOFF + C + c] = 0.f;
    float rv = fmaxf(r[0], 1.0f);  // jnp.clip(r, 1.0)
    float eh[NT], ew[NT];
    for (int j = 0; j < NT; ++j) { eh[j] = 0.f; ew[j] = 0.f; }
    for (int i = 0; i < KT; ++i) {
        float kpos  = (float)(i - KT / 2);
        float delta = kpos * rv;
        float d0f   = floorf(delta);
        float fr    = delta - d0f;
        int   j0    = (int)d0f + M;
        float whv = wh[c * KT + i];
        float wwv = ww[c * KT + i];
        if (j0 >= 0 && j0 < NT)         { eh[j0]   += (1.f - fr) * whv; ew[j0]   += (1.f - fr) * wwv; }
        if (j0 + 1 >= 0 && j0 + 1 < NT) { eh[j0+1] += fr * whv;         ew[j0+1] += fr * wwv; }
    }
    for (int j = 0; j < NT; ++j) {
        taps[c * NT + j]          = eh[j];
        taps[C * NT + c * NT + j] = ew[j];
    }
}

__global__ __launch_bounds__(BLOCK) void deform_axial_kernel(
    const float* __restrict__ x, const float* __restrict__ taps,
    float* __restrict__ out) {
    __shared__ float lds[2 * BUF_FLOATS];   // 81,920 B -> exactly 2 blocks/CU

    const int p    = blockIdx.x;      // plane (b*C + c) -- block-uniform
    const int c    = p & (C - 1);     // uniform -> taps via scalar loads
    const int tid  = threadIdx.x;
    const int wave = tid >> 6;
    const int lane = tid & 63;

    const long base = (long)p * (H * W);
    const float* __restrict__ xp = x + base;

    // per-channel effective taps: block-uniform address -> SGPRs
    float eh[NT], ew[NT];
    const float* __restrict__ ehp = taps + c * NT;
    const float* __restrict__ ewp = taps + C * NT + c * NT;
#pragma unroll
    for (int j = 0; j < NT; ++j) { eh[j] = ehp[j]; ew[j] = ewp[j]; }
    // insurance: if taps came in as vector loads, drain them so the manual
    // vmcnt bookkeeping below starts from 0 outstanding vmem ops.
    asm volatile("s_waitcnt vmcnt(0)" ::: "memory");

    const float* zbase = taps + ZOFF + lane * 4;  // per-lane 16B zero slot

    // ---- stage tile t's 44-row window into buffer `buf` (6 DMAs per wave) ----
    auto STAGE = [&](int buf, int t) {
        const int h0 = t * TH;
        float* ldsb = lds + buf * BUF_FLOATS;
#pragma unroll
        for (int k = 0; k < 6; ++k) {
            const int m   = wave * 6 + k;            // chunk 0..41
            const int q   = m * 64 + lane;           // staging quad index
            const int row = q / WQ;
            const int col = q - row * WQ;
            const int grow = h0 - M + row;
            const bool valid = (q < NSTAGE) & ((unsigned)grow < (unsigned)H);
            const float* src = valid ? (xp + grow * W + col * 4) : zbase;
            float* dst = ldsb + (m < CHUNKS ? m : CHUNKS) * 256;  // dummies -> scratch
            __builtin_amdgcn_global_load_lds((gbl_u32*)src, (lds_u32*)dst, 16, 0, 0);
        }
    };

    auto BAR = []() {
        asm volatile("" ::: "memory");
        __builtin_amdgcn_s_barrier();
        asm volatile("" ::: "memory");
    };

    // compute geometry (fixed per thread)
    const int cq = tid % WQ;        // column quad 0..55
    const int rg = tid / WQ;        // row group 0..7
    const int r0 = rg * RPT;        // first output row within tile
    const float4 zero4 = make_float4(0.f, 0.f, 0.f, 0.f);

    // ---- compute tile t from buffer `buf`, store to out (4 stores/thread) ----
    auto COMPUTE = [&](int buf, int t) {
        const float* ldsb = lds + buf * BUF_FLOATS;
        const int h0 = t * TH;

        float4 acc[RPT];
#pragma unroll
        for (int k = 0; k < RPT; ++k) acc[k] = zero4;

#pragma unroll
        for (int s = 0; s < WROWS; ++s) {
            const float4 q = *reinterpret_cast<const float4*>(&ldsb[(r0 + s) * W + cq * 4]);

            // H-axis: streamed row s is tap j = s-k for output row k
#pragma unroll
            for (int k = 0; k < RPT; ++k) {
                const int j = s - k;
                if (j >= 0 && j < NT) {
                    const float wgt = eh[j];
                    acc[k].x = fmaf(wgt, q.x, acc[k].x);
                    acc[k].y = fmaf(wgt, q.y, acc[k].y);
                    acc[k].z = fmaf(wgt, q.z, acc[k].z);
                    acc[k].w = fmaf(wgt, q.w, acc[k].w);
                }
            }

            // center row for output k = s - M: identity + W-conv
            if (s >= M && s < M + RPT) {
                const int k = s - M;
                const float* crow = &ldsb[(r0 + s) * W];
                float4 qm2 = (cq >= 2)      ? *reinterpret_cast<const float4*>(crow + (cq - 2) * 4) : zero4;
                float4 qm1 = (cq >= 1)      ? *reinterpret_cast<const float4*>(crow + (cq - 1) * 4) : zero4;
                float4 qp1 = (cq <= WQ - 2) ? *reinterpret_cast<const float4*>(crow + (cq + 1) * 4) : zero4;
                float4 qp2 = (cq <= WQ - 3) ? *reinterpret_cast<const float4*>(crow + (cq + 2) * 4) : zero4;

                float win[20];
                win[ 0] = qm2.x; win[ 1] = qm2.y; win[ 2] = qm2.z; win[ 3] = qm2.w;
                win[ 4] = qm1.x; win[ 5] = qm1.y; win[ 6] = qm1.z; win[ 7] = qm1.w;
                win[ 8] = q.x;   win[ 9] = q.y;   win[10] = q.z;   win[11] = q.w;
                win[12] = qp1.x; win[13] = qp1.y; win[14] = qp1.z; win[15] = qp1.w;
                win[16] = qp2.x; win[17] = qp2.y; win[18] = qp2.z; win[19] = qp2.w;

                acc[k].x += q.x; acc[k].y += q.y; acc[k].z += q.z; acc[k].w += q.w;
#pragma unroll
                for (int j = 0; j < NT; ++j) {
                    const float wgt = ew[j];
                    acc[k].x = fmaf(wgt, win[2 + j], acc[k].x);
                    acc[k].y = fmaf(wgt, win[3 + j], acc[k].y);
                    acc[k].z = fmaf(wgt, win[4 + j], acc[k].z);
                    acc[k].w = fmaf(wgt, win[5 + j], acc[k].w);
                }
            }
        }

        float* outp = out + base + (long)(h0 + r0) * W + cq * 4;
#pragma unroll
        for (int k = 0; k < RPT; ++k) {
            *reinterpret_cast<float4*>(outp + k * W) = acc[k];
        }
    };

    // ---- pipeline: per-wave vmem order is [6 DMA][4 st][6 DMA][4 st]... ----
    STAGE(0, 0);                                          // S0
    STAGE(1, 1);                                          // S1
    asm volatile("s_waitcnt vmcnt(6)" ::: "memory");      // S0 done (S1 in flight)
    BAR();
    COMPUTE(0, 0);                                        // + stores(0)
    BAR();

    for (int t = 1; t <= 5; ++t) {
        STAGE((t + 1) & 1, t + 1);                        // S(t+1)
        // newest 10 = stores(t-1)[4] + S(t+1)[6]  =>  S(t) complete
        asm volatile("s_waitcnt vmcnt(10)" ::: "memory");
        BAR();
        COMPUTE(t & 1, t);                                // + stores(t)
        BAR();
    }

    // newest 4 = stores(5)  =>  S6 complete
    asm volatile("s_waitcnt vmcnt(4)" ::: "memory");
    BAR();
    COMPUTE(0, 6);
}

extern "C" void kernel_launch(void* const* d_in, const int* in_sizes, int n_in,
                              void* d_out, int out_size, void* d_ws, size_t ws_size,
                              hipStream_t stream) {
    const float* x  = (const float*)d_in[0];
    const float* wh = (const float*)d_in[1];
    const float* ww = (const float*)d_in[2];
    const float* r  = (const float*)d_in[3];
    float* out  = (float*)d_out;
    float* taps = (float*)d_ws;  // needs (2*C*NT + 256)*4 = 14,336 bytes

    hipLaunchKernelGGL(taps_kernel, dim3(1), dim3(C), 0, stream, wh, ww, r, taps);
    hipLaunchKernelGGL(deform_axial_kernel, dim3(B * C), dim3(BLOCK),
                       0, stream, x, taps, out);
}